// Round 3
// baseline (122.759 us; speedup 1.0000x reference)
//
#include <hip/hip_runtime.h>
#include <hip/hip_bf16.h>

#define HDIM 2048

// ---------------------------------------------------------------------------
// Feature MLP: feat(462) -> fd1(66) -> fd2(66). One block, 512 threads.
// f1: one wave per output row, lanes stride the 462-dim (coalesced), shuffle
// reduce. f2: tiny, one thread per output.
// ---------------------------------------------------------------------------
__global__ __launch_bounds__(512) void mlp_kernel(
    const float* __restrict__ feat,      // 462
    const float* __restrict__ f1_w,      // (66,462)
    const float* __restrict__ f1_b,      // 66
    const float* __restrict__ f2_w,      // (66,66)
    const float* __restrict__ f2_b,      // 66
    float* __restrict__ fd2_out)         // 66
{
    __shared__ float fd1[66];
    const int wid  = threadIdx.x >> 6;   // 0..7
    const int lane = threadIdx.x & 63;

    for (int o = wid; o < 66; o += 8) {
        const float* row = f1_w + o * 462;
        float s = 0.f;
        for (int k = lane; k < 462; k += 64) s = fmaf(row[k], feat[k], s);
#pragma unroll
        for (int off = 32; off > 0; off >>= 1) s += __shfl_down(s, off);
        if (lane == 0) fd1[o] = s + f1_b[o];
    }
    __syncthreads();
    const int t = threadIdx.x;
    if (t < 66) {
        float s = f2_b[t];
        const float* row = f2_w + t * 66;
        for (int k = 0; k < 66; ++k) s = fmaf(row[k], fd1[k], s);
        fd2_out[t] = s;
    }
}

// ---------------------------------------------------------------------------
// hid = h0 @ emb_w.T + emb_b + (fd2 @ f3_w.T + f3_b).  One thread per output,
// float2-vectorized row reads (rows are 8B-aligned: 34 and 66 even counts).
// ---------------------------------------------------------------------------
__global__ __launch_bounds__(256) void hid_kernel(
    const float* __restrict__ h0,        // 34
    const float* __restrict__ emb_w,     // (H,34)
    const float* __restrict__ emb_b,     // H
    const float* __restrict__ f3_w,      // (H,66)
    const float* __restrict__ f3_b,      // H
    const float* __restrict__ fd2,       // 66
    float* __restrict__ h_out)           // H
{
    __shared__ float s_h0[34];
    __shared__ float s_fd2[66];
    const int t = threadIdx.x;
    if (t < 34) s_h0[t] = h0[t];
    if (t < 66) s_fd2[t] = fd2[t];
    __syncthreads();

    const int j = blockIdx.x * blockDim.x + t;
    if (j >= HDIM) return;
    float s = emb_b[j] + f3_b[j];
    const float2* er = (const float2*)(emb_w + j * 34);
#pragma unroll
    for (int k = 0; k < 17; ++k) {
        const float2 w = er[k];
        s = fmaf(w.x, s_h0[2 * k], fmaf(w.y, s_h0[2 * k + 1], s));
    }
    const float2* fr = (const float2*)(f3_w + j * 66);
#pragma unroll
    for (int k = 0; k < 33; ++k) {
        const float2 w = fr[k];
        s = fmaf(w.x, s_fd2[2 * k], fmaf(w.y, s_fd2[2 * k + 1], s));
    }
    h_out[j] = s;
}

// ---------------------------------------------------------------------------
// One GRU step, split-K x2: each block (256 thr = 4 waves) handles 2 output
// rows; each row's three H-length dots are split across 2 waves (half the K
// range each). 1024 blocks -> 4096 waves -> 4 waves/SIMD (2x R2's MLP).
// Coalesced float4 loads; h float4s reused for all 3 gate rows.
// ---------------------------------------------------------------------------
__global__ __launch_bounds__(256) void gru_step_kernel(
    const float* __restrict__ w_hh,      // (3H,H)   [already offset to step]
    const float* __restrict__ w_ih,      // (3H)     [col 0; already offset]
    const float* __restrict__ b_ih,      // (3H)
    const float* __restrict__ b_hh,      // (3H)
    const float* __restrict__ xt,        // (7)
    const int step,
    const float* __restrict__ h_in,      // H
    float* __restrict__ h_out)           // H
{
    __shared__ float part[4][3];

    const int wid  = threadIdx.x >> 6;           // 0..3
    const int lane = threadIdx.x & 63;
    const int row  = blockIdx.x * 2 + (wid >> 1);  // output row j
    const int half = wid & 1;                      // K-half: 0 or 1

    // float4 index space: 512 float4s per row; this wave covers 256 of them.
    const int base4 = half * 256;
    const float4* hv4 = (const float4*)h_in + base4;
    const float4* wr  = (const float4*)(w_hh + (size_t)row * HDIM) + base4;
    const float4* wz  = (const float4*)(w_hh + (size_t)(HDIM + row) * HDIM) + base4;
    const float4* wn  = (const float4*)(w_hh + (size_t)(2 * HDIM + row) * HDIM) + base4;

    float sr = 0.f, sz = 0.f, sn = 0.f;
#pragma unroll
    for (int i = 0; i < 4; ++i) {
        const int idx = i * 64 + lane;           // 0..255
        const float4 h4 = hv4[idx];
        const float4 a  = wr[idx];
        const float4 b  = wz[idx];
        const float4 c  = wn[idx];
        sr = fmaf(a.x, h4.x, fmaf(a.y, h4.y, fmaf(a.z, h4.z, fmaf(a.w, h4.w, sr))));
        sz = fmaf(b.x, h4.x, fmaf(b.y, h4.y, fmaf(b.z, h4.z, fmaf(b.w, h4.w, sz))));
        sn = fmaf(c.x, h4.x, fmaf(c.y, h4.y, fmaf(c.z, h4.z, fmaf(c.w, h4.w, sn))));
    }
#pragma unroll
    for (int off = 32; off > 0; off >>= 1) {
        sr += __shfl_down(sr, off);
        sz += __shfl_down(sz, off);
        sn += __shfl_down(sn, off);
    }
    if (lane == 0) {
        part[wid][0] = sr;
        part[wid][1] = sz;
        part[wid][2] = sn;
    }
    __syncthreads();

    const int t = threadIdx.x;
    if (t < 2) {
        const int j = blockIdx.x * 2 + t;
        const float psr = part[2 * t][0] + part[2 * t + 1][0];
        const float psz = part[2 * t][1] + part[2 * t + 1][1];
        const float psn = part[2 * t][2] + part[2 * t + 1][2];
        const float x = xt[step];
        const float gir = fmaf(x, w_ih[j],            b_ih[j]);
        const float giz = fmaf(x, w_ih[HDIM + j],     b_ih[HDIM + j]);
        const float gin = fmaf(x, w_ih[2 * HDIM + j], b_ih[2 * HDIM + j]);
        const float ghr = psr + b_hh[j];
        const float ghz = psz + b_hh[HDIM + j];
        const float ghn = psn + b_hh[2 * HDIM + j];
        const float r = 1.f / (1.f + expf(-(gir + ghr)));
        const float z = 1.f / (1.f + expf(-(giz + ghz)));
        const float n = tanhf(fmaf(r, ghn, gin));
        h_out[j] = fmaf(z, h_in[j] - n, n);   // (1-z)*n + z*h
    }
}

// ---------------------------------------------------------------------------
// out = h7 . out_w[0:H] + restrict*out_w[H] + number*out_w[H+1] + out_b
// Output is FLOAT32.
// ---------------------------------------------------------------------------
__global__ __launch_bounds__(256) void out_kernel(
    const float* __restrict__ h7,        // H
    const float* __restrict__ out_w,     // H+2
    const float* __restrict__ out_b,     // 1
    const float* __restrict__ restr,     // 1
    const float* __restrict__ number,    // 1
    float* __restrict__ out)             // 1 (fp32)
{
    __shared__ float red[256];
    const int t = threadIdx.x;
    float s = 0.f;
    for (int k = t; k < HDIM; k += 256) s = fmaf(out_w[k], h7[k], s);
    red[t] = s;
    __syncthreads();
#pragma unroll
    for (int off = 128; off > 0; off >>= 1) {
        if (t < off) red[t] += red[t + off];
        __syncthreads();
    }
    if (t == 0) {
        out[0] = red[0] + restr[0] * out_w[HDIM] + number[0] * out_w[HDIM + 1]
               + out_b[0];
    }
}

// ---------------------------------------------------------------------------
extern "C" void kernel_launch(void* const* d_in, const int* in_sizes, int n_in,
                              void* d_out, int out_size, void* d_ws, size_t ws_size,
                              hipStream_t stream) {
    const float* xt     = (const float*)d_in[0];
    const float* h0     = (const float*)d_in[1];
    const float* feat   = (const float*)d_in[2];
    const float* number = (const float*)d_in[3];
    const float* restr  = (const float*)d_in[4];
    const float* w_ih   = (const float*)d_in[5];
    const float* w_hh   = (const float*)d_in[6];
    const float* b_ih   = (const float*)d_in[7];
    const float* b_hh   = (const float*)d_in[8];
    const float* emb_w  = (const float*)d_in[9];
    const float* emb_b  = (const float*)d_in[10];
    const float* f1_w   = (const float*)d_in[11];
    const float* f1_b   = (const float*)d_in[12];
    const float* f2_w   = (const float*)d_in[13];
    const float* f2_b   = (const float*)d_in[14];
    const float* f3_w   = (const float*)d_in[15];
    const float* f3_b   = (const float*)d_in[16];
    const float* out_w  = (const float*)d_in[17];
    const float* out_b  = (const float*)d_in[18];

    float* ws    = (float*)d_ws;
    float* fd2   = ws;              // 66 floats
    float* hbuf0 = ws + 256;        // H floats
    float* hbuf1 = ws + 256 + HDIM; // H floats

    mlp_kernel<<<1, 512, 0, stream>>>(feat, f1_w, f1_b, f2_w, f2_b, fd2);
    hid_kernel<<<HDIM / 256, 256, 0, stream>>>(h0, emb_w, emb_b, f3_w, f3_b, fd2,
                                               hbuf0);

    float* bufs[2] = {hbuf0, hbuf1};
    for (int s = 0; s < 7; ++s) {
        const float* hin = bufs[s & 1];
        float* hout      = bufs[(s + 1) & 1];
        gru_step_kernel<<<HDIM / 2, 256, 0, stream>>>(
            w_hh + (size_t)s * 3 * HDIM * HDIM,
            w_ih + (size_t)s * 3 * HDIM,
            b_ih + (size_t)s * 3 * HDIM,
            b_hh + (size_t)s * 3 * HDIM,
            xt, s, hin, hout);
    }

    out_kernel<<<1, 256, 0, stream>>>(bufs[7 & 1], out_w, out_b, restr, number,
                                      (float*)d_out);
}